// Round 1
// baseline (492.711 us; speedup 1.0000x reference)
//
#include <hip/hip_runtime.h>

// Problem constants
#define NN 50000
#define EE 800000
#define FF 256   // IN = HID = PROJ = 256

typedef float    f32x4 __attribute__((ext_vector_type(4)));
typedef _Float16 f16x8 __attribute__((ext_vector_type(8)));
typedef _Float16 f16x4 __attribute__((ext_vector_type(4)));

// ---------------------------------------------------------------------------
// CSR build kernels
// ---------------------------------------------------------------------------

// ec[d] += 1 for every edge with dst d (self-loops handled analytically later)
__global__ void count_kernel(const int* __restrict__ ei, int* __restrict__ ec) {
    int e = blockIdx.x * 256 + threadIdx.x;
    if (e < EE) atomicAdd(&ec[ei[EE + e]], 1);
}

// dinv[i] = rsqrt(deg), deg = edge_count + 1 (self loop) >= 1
__global__ void dinv_kernel(const int* __restrict__ ec, float* __restrict__ dinv) {
    int i = blockIdx.x * 256 + threadIdx.x;
    if (i < NN) dinv[i] = rsqrtf((float)(ec[i] + 1));
}

// single-block exclusive scan of ec -> rs (N+1 entries)
__global__ void scan_kernel(const int* __restrict__ ec, int* __restrict__ rs) {
    __shared__ int s[1024];
    const int t = threadIdx.x;
    const int CH = (NN + 1023) / 1024;           // 49
    int start = t * CH;
    int end   = start + CH; if (end > NN) end = NN;
    if (start > NN) start = NN;
    int sum = 0;
    for (int i = start; i < end; ++i) sum += ec[i];
    s[t] = sum;
    __syncthreads();
    // Hillis-Steele inclusive scan over 1024 partials
    for (int off = 1; off < 1024; off <<= 1) {
        int v = (t >= off) ? s[t - off] : 0;
        __syncthreads();
        s[t] += v;
        __syncthreads();
    }
    int excl = s[t] - sum;                        // exclusive prefix of this chunk
    for (int i = start; i < end; ++i) { rs[i] = excl; excl += ec[i]; }
    if (t == 1023) rs[NN] = excl;                 // == EE
}

// scatter edges into CSR slots; store src index and weight dinv[src]
__global__ void fill_kernel(const int* __restrict__ ei, const int* __restrict__ rs,
                            int* __restrict__ cnt, const float* __restrict__ dinv,
                            int* __restrict__ csrc, float* __restrict__ cw) {
    int e = blockIdx.x * 256 + threadIdx.x;
    if (e >= EE) return;
    int s = ei[e];
    int d = ei[EE + e];
    int p = rs[d] + atomicAdd(&cnt[d], 1);
    csrc[p] = s;
    cw[p]   = dinv[s];
}

// ---------------------------------------------------------------------------
// W pack: fp32 [K=256][N=256] row-major -> transposed fp16 hi/lo [n][k]
// wp layout: [layer*2 + hi/lo][65536]
// ---------------------------------------------------------------------------
__global__ void packw_kernel(const float* __restrict__ W1, const float* __restrict__ W2,
                             _Float16* __restrict__ wp) {
    int idx = blockIdx.x * 256 + threadIdx.x;     // 65536 threads
    int k = idx >> 8, n = idx & 255;
    float w1 = W1[k * 256 + n];
    _Float16 h1 = (_Float16)w1;
    wp[0 * 65536 + n * 256 + k] = h1;
    wp[1 * 65536 + n * 256 + k] = (_Float16)(w1 - (float)h1);
    float w2 = W2[k * 256 + n];
    _Float16 h2 = (_Float16)w2;
    wp[2 * 65536 + n * 256 + k] = h2;
    wp[3 * 65536 + n * 256 + k] = (_Float16)(w2 - (float)h2);
}

// ---------------------------------------------------------------------------
// GEMM: H(fp16)[50000][256] = X(fp32) @ W  via fp16 MFMA, W = Whi + Wlo.
// Block = 256 thr (4 waves, 2x2), tile 128x128, K-iter = 32.
// ---------------------------------------------------------------------------
#define LDA 40   // padded fp16 leading dim (32 + 8): 2-way LDS bank aliasing only

__global__ __launch_bounds__(256) void gemm_kernel(
    const float* __restrict__ X, const _Float16* __restrict__ Bhi,
    const _Float16* __restrict__ Blo, _Float16* __restrict__ H) {
    __shared__ _Float16 As[128 * LDA];
    __shared__ _Float16 Bh[128 * LDA];
    __shared__ _Float16 Bl[128 * LDA];

    const int tid  = threadIdx.x;
    const int lane = tid & 63;
    const int w    = tid >> 6;
    const int wm   = w & 1, wn = w >> 1;
    const int q    = lane >> 4;       // quad -> k-group
    const int l16  = lane & 15;
    const int m0   = blockIdx.y * 128;
    const int n0   = blockIdx.x * 128;

    f32x4 acc[4][4] = {};             // [mt][nt], 16 tiles of 16x16

    for (int kt = 0; kt < 8; ++kt) {
        // --- stage A: 128 rows x 32 k of fp32 X, convert to fp16 ---
#pragma unroll
        for (int c = tid; c < 1024; c += 256) {   // 16B fp32 granules
            int row = c >> 3, c4 = c & 7;
            int gm = m0 + row; if (gm > NN - 1) gm = NN - 1;
            f32x4 v = *(const f32x4*)(X + (size_t)gm * FF + kt * 32 + c4 * 4);
            f16x4 hv;
            hv.x = (_Float16)v.x; hv.y = (_Float16)v.y;
            hv.z = (_Float16)v.z; hv.w = (_Float16)v.w;
            *(f16x4*)(As + row * LDA + c4 * 4) = hv;
        }
        // --- stage B hi/lo: 128 n x 32 k fp16 (pre-transposed, contiguous k) ---
#pragma unroll
        for (int c = tid; c < 512; c += 256) {    // 16B fp16 granules
            int n = c >> 2, k8 = c & 3;
            f16x8 vh = *(const f16x8*)(Bhi + (size_t)(n0 + n) * FF + kt * 32 + k8 * 8);
            *(f16x8*)(Bh + n * LDA + k8 * 8) = vh;
            f16x8 vl = *(const f16x8*)(Blo + (size_t)(n0 + n) * FF + kt * 32 + k8 * 8);
            *(f16x8*)(Bl + n * LDA + k8 * 8) = vl;
        }
        __syncthreads();

        f16x8 af[4], bhf[4], blf[4];
#pragma unroll
        for (int mt = 0; mt < 4; ++mt)
            af[mt] = *(const f16x8*)(As + (wm * 64 + mt * 16 + l16) * LDA + q * 8);
#pragma unroll
        for (int nt = 0; nt < 4; ++nt) {
            bhf[nt] = *(const f16x8*)(Bh + (wn * 64 + nt * 16 + l16) * LDA + q * 8);
            blf[nt] = *(const f16x8*)(Bl + (wn * 64 + nt * 16 + l16) * LDA + q * 8);
        }
#pragma unroll
        for (int mt = 0; mt < 4; ++mt)
#pragma unroll
            for (int nt = 0; nt < 4; ++nt) {
                acc[mt][nt] = __builtin_amdgcn_mfma_f32_16x16x32_f16(af[mt], bhf[nt], acc[mt][nt], 0, 0, 0);
                acc[mt][nt] = __builtin_amdgcn_mfma_f32_16x16x32_f16(af[mt], blf[nt], acc[mt][nt], 0, 0, 0);
            }
        __syncthreads();
    }

    // epilogue: C/D layout col = lane&15, row = quad*4 + reg
#pragma unroll
    for (int mt = 0; mt < 4; ++mt)
#pragma unroll
        for (int r = 0; r < 4; ++r) {
            int m = m0 + wm * 64 + mt * 16 + q * 4 + r;
            if (m < NN) {
#pragma unroll
                for (int nt = 0; nt < 4; ++nt) {
                    int n = n0 + wn * 64 + nt * 16 + l16;
                    H[(size_t)m * FF + n] = (_Float16)acc[mt][nt][r];
                }
            }
        }
}

// ---------------------------------------------------------------------------
// Aggregation + bias + PReLU. One wave per row; lane owns 4 features.
// out[i] = prelu( dinv[i]*( sum_e w_e*h[src_e] + dinv[i]*h[i] ) + b, a )
// ---------------------------------------------------------------------------
__global__ __launch_bounds__(256) void agg_kernel(
    const _Float16* __restrict__ H, const int* __restrict__ rs,
    const int* __restrict__ csrc, const float* __restrict__ cw,
    const float* __restrict__ dinv, const float* __restrict__ bias,
    const float* __restrict__ a_ptr, float* __restrict__ out) {
    const int row  = blockIdx.x * 4 + (threadIdx.x >> 6);
    const int lane = threadIdx.x & 63;
    if (row >= NN) return;

    const float av = a_ptr[0];
    const float di = dinv[row];

    f16x4 hv = *(const f16x4*)(H + (size_t)row * FF + lane * 4);
    float ax = di * (float)hv.x;
    float ay = di * (float)hv.y;
    float az = di * (float)hv.z;
    float aw = di * (float)hv.w;

    int e   = rs[row];
    int end = rs[row + 1];
    for (; e + 1 < end; e += 2) {
        int   s0 = csrc[e],   s1 = csrc[e + 1];
        float w0 = cw[e],     w1 = cw[e + 1];
        f16x4 h0 = *(const f16x4*)(H + (size_t)s0 * FF + lane * 4);
        f16x4 h1 = *(const f16x4*)(H + (size_t)s1 * FF + lane * 4);
        ax += w0 * (float)h0.x + w1 * (float)h1.x;
        ay += w0 * (float)h0.y + w1 * (float)h1.y;
        az += w0 * (float)h0.z + w1 * (float)h1.z;
        aw += w0 * (float)h0.w + w1 * (float)h1.w;
    }
    if (e < end) {
        int   s0 = csrc[e];
        float w0 = cw[e];
        f16x4 h0 = *(const f16x4*)(H + (size_t)s0 * FF + lane * 4);
        ax += w0 * (float)h0.x;
        ay += w0 * (float)h0.y;
        az += w0 * (float)h0.z;
        aw += w0 * (float)h0.w;
    }

    f32x4 bv = *(const f32x4*)(bias + lane * 4);
    float r0 = di * ax + bv.x; r0 = (r0 >= 0.f) ? r0 : av * r0;
    float r1 = di * ay + bv.y; r1 = (r1 >= 0.f) ? r1 : av * r1;
    float r2 = di * az + bv.z; r2 = (r2 >= 0.f) ? r2 : av * r2;
    float r3 = di * aw + bv.w; r3 = (r3 >= 0.f) ? r3 : av * r3;
    f32x4 res = {r0, r1, r2, r3};
    *(f32x4*)(out + (size_t)row * FF + lane * 4) = res;
}

// ---------------------------------------------------------------------------
// Launch
// ---------------------------------------------------------------------------
extern "C" void kernel_launch(void* const* d_in, const int* in_sizes, int n_in,
                              void* d_out, int out_size, void* d_ws, size_t ws_size,
                              hipStream_t stream) {
    const float* x  = (const float*)d_in[0];
    const float* W1 = (const float*)d_in[1];
    const float* b1 = (const float*)d_in[2];
    const float* W2 = (const float*)d_in[3];
    const float* b2 = (const float*)d_in[4];
    const float* a  = (const float*)d_in[5];
    const int*   ei = (const int*)d_in[6];
    float* out = (float*)d_out;

    char* ws = (char*)d_ws;
    size_t off = 0;
    auto carve = [&](size_t bytes) -> char* {
        char* p = ws + off;
        off = (off + bytes + 255) & ~(size_t)255;
        return p;
    };
    int*      ec   = (int*)carve((size_t)NN * 4);
    int*      cnt  = (int*)carve((size_t)NN * 4);
    int*      rs   = (int*)carve((size_t)(NN + 1) * 4);
    float*    dinv = (float*)carve((size_t)NN * 4);
    int*      csrc = (int*)carve((size_t)EE * 4);
    float*    cw   = (float*)carve((size_t)EE * 4);
    _Float16* wp   = (_Float16*)carve((size_t)4 * 65536 * 2);
    _Float16* h    = (_Float16*)carve((size_t)NN * FF * 2);

    hipMemsetAsync(ec, 0, (size_t)NN * 4, stream);
    hipMemsetAsync(cnt, 0, (size_t)NN * 4, stream);

    count_kernel<<<(EE + 255) / 256, 256, 0, stream>>>(ei, ec);
    dinv_kernel<<<(NN + 255) / 256, 256, 0, stream>>>(ec, dinv);
    scan_kernel<<<1, 1024, 0, stream>>>(ec, rs);
    fill_kernel<<<(EE + 255) / 256, 256, 0, stream>>>(ei, rs, cnt, dinv, csrc, cw);
    packw_kernel<<<256, 256, 0, stream>>>(W1, W2, wp);

    // layer 1
    gemm_kernel<<<dim3(2, 391), 256, 0, stream>>>(x, wp + 0 * 65536, wp + 1 * 65536, h);
    agg_kernel<<<(NN + 3) / 4, 256, 0, stream>>>(h, rs, csrc, cw, dinv, b1, a, out);
    // layer 2
    gemm_kernel<<<dim3(2, 391), 256, 0, stream>>>(out, wp + 2 * 65536, wp + 3 * 65536, h);
    agg_kernel<<<(NN + 3) / 4, 256, 0, stream>>>(h, rs, csrc, cw, dinv, b2, a, out);
}

// Round 2
// 425.148 us; speedup vs baseline: 1.1589x; 1.1589x over previous
//
#include <hip/hip_runtime.h>

// Problem constants
#define NN 50000
#define EE 800000
#define FF 256   // IN = HID = PROJ = 256
#define NBLK 196 // ceil(NN/256)

typedef float    f32x4 __attribute__((ext_vector_type(4)));
typedef _Float16 f16x8 __attribute__((ext_vector_type(8)));
typedef _Float16 f16x4 __attribute__((ext_vector_type(4)));

// ---------------------------------------------------------------------------
// CSR build kernels
// ---------------------------------------------------------------------------

// ec[d] += 1 for every edge with dst d (self-loops handled analytically later)
__global__ void count_kernel(const int* __restrict__ ei, int* __restrict__ ec) {
    int e = blockIdx.x * 256 + threadIdx.x;
    if (e < EE) atomicAdd(&ec[ei[EE + e]], 1);
}

// ---- two-level scan: part-sums -> scan of 196 partials -> final scan ------

// per-block (256-elem) sum of ec -> bsum[blockIdx]
__global__ __launch_bounds__(256) void scan_part(const int* __restrict__ ec,
                                                 int* __restrict__ bsum) {
    int i = blockIdx.x * 256 + threadIdx.x;
    int v = (i < NN) ? ec[i] : 0;
#pragma unroll
    for (int d = 1; d < 64; d <<= 1) v += __shfl_xor(v, d);
    __shared__ int wt[4];
    int lane = threadIdx.x & 63, wid = threadIdx.x >> 6;
    if (lane == 0) wt[wid] = v;
    __syncthreads();
    if (threadIdx.x == 0)
        bsum[blockIdx.x] = wt[0] + wt[1] + wt[2] + wt[3];
}

// single small block: exclusive scan of 196 partials -> boff; rs[NN] = total
__global__ __launch_bounds__(256) void scan_mid(const int* __restrict__ bsum,
                                                int* __restrict__ boff,
                                                int* __restrict__ rs) {
    const int t = threadIdx.x;
    int v = (t < NBLK) ? bsum[t] : 0;
    int lane = t & 63, wid = t >> 6;
    int x = v;
#pragma unroll
    for (int d = 1; d < 64; d <<= 1) {
        int u = __shfl_up(x, d);
        if (lane >= d) x += u;
    }
    __shared__ int wt[4];
    if (lane == 63) wt[wid] = x;
    __syncthreads();
    int add = 0;
    for (int wi = 0; wi < wid; ++wi) add += wt[wi];
    x += add;                                   // inclusive scan
    if (t < NBLK) boff[t] = x - v;              // exclusive
    if (t == NBLK - 1) rs[NN] = x;              // total == EE
}

// final: block-local exclusive scan + block offset -> rs; also dinv
__global__ __launch_bounds__(256) void scan_final(const int* __restrict__ ec,
                                                  const int* __restrict__ boff,
                                                  int* __restrict__ rs,
                                                  float* __restrict__ dinv) {
    int i = blockIdx.x * 256 + threadIdx.x;
    int v = (i < NN) ? ec[i] : 0;
    int lane = threadIdx.x & 63, wid = threadIdx.x >> 6;
    int x = v;
#pragma unroll
    for (int d = 1; d < 64; d <<= 1) {
        int u = __shfl_up(x, d);
        if (lane >= d) x += u;
    }
    __shared__ int wt[4];
    if (lane == 63) wt[wid] = x;
    __syncthreads();
    int add = 0;
    for (int wi = 0; wi < wid; ++wi) add += wt[wi];
    x += add;                                   // block-inclusive
    if (i < NN) {
        rs[i]   = x - v + boff[blockIdx.x];     // global exclusive
        dinv[i] = rsqrtf((float)(v + 1));       // deg = edges + self-loop
    }
}

// scatter edges into CSR slots; store src index and weight dinv[src]
__global__ void fill_kernel(const int* __restrict__ ei, const int* __restrict__ rs,
                            int* __restrict__ cnt, const float* __restrict__ dinv,
                            int* __restrict__ csrc, float* __restrict__ cw) {
    int e = blockIdx.x * 256 + threadIdx.x;
    if (e >= EE) return;
    int s = ei[e];
    int d = ei[EE + e];
    int p = rs[d] + atomicAdd(&cnt[d], 1);
    csrc[p] = s;
    cw[p]   = dinv[s];
}

// ---------------------------------------------------------------------------
// W pack: fp32 [K=256][N=256] row-major -> transposed fp16 hi/lo [n][k]
// wp layout: [layer*2 + hi/lo][65536]
// ---------------------------------------------------------------------------
__global__ void packw_kernel(const float* __restrict__ W1, const float* __restrict__ W2,
                             _Float16* __restrict__ wp) {
    int idx = blockIdx.x * 256 + threadIdx.x;     // 65536 threads
    int k = idx >> 8, n = idx & 255;
    float w1 = W1[k * 256 + n];
    _Float16 h1 = (_Float16)w1;
    wp[0 * 65536 + n * 256 + k] = h1;
    wp[1 * 65536 + n * 256 + k] = (_Float16)(w1 - (float)h1);
    float w2 = W2[k * 256 + n];
    _Float16 h2 = (_Float16)w2;
    wp[2 * 65536 + n * 256 + k] = h2;
    wp[3 * 65536 + n * 256 + k] = (_Float16)(w2 - (float)h2);
}

// ---------------------------------------------------------------------------
// GEMM: H(fp16)[50000][256] = X(fp32) @ W  via fp16 MFMA, W = Whi + Wlo.
// Block = 256 thr (4 waves, 2x2), tile 128x128, K-iter = 32.
// ---------------------------------------------------------------------------
#define LDA 40   // padded fp16 leading dim (32 + 8): 2-way LDS bank aliasing only

__global__ __launch_bounds__(256) void gemm_kernel(
    const float* __restrict__ X, const _Float16* __restrict__ Bhi,
    const _Float16* __restrict__ Blo, _Float16* __restrict__ H) {
    __shared__ _Float16 As[128 * LDA];
    __shared__ _Float16 Bh[128 * LDA];
    __shared__ _Float16 Bl[128 * LDA];

    const int tid  = threadIdx.x;
    const int lane = tid & 63;
    const int w    = tid >> 6;
    const int wm   = w & 1, wn = w >> 1;
    const int q    = lane >> 4;       // quad -> k-group
    const int l16  = lane & 15;
    const int m0   = blockIdx.y * 128;
    const int n0   = blockIdx.x * 128;

    f32x4 acc[4][4] = {};             // [mt][nt], 16 tiles of 16x16

    for (int kt = 0; kt < 8; ++kt) {
        // --- stage A: 128 rows x 32 k of fp32 X, convert to fp16 ---
#pragma unroll
        for (int c = tid; c < 1024; c += 256) {   // 16B fp32 granules
            int row = c >> 3, c4 = c & 7;
            int gm = m0 + row; if (gm > NN - 1) gm = NN - 1;
            f32x4 v = *(const f32x4*)(X + (size_t)gm * FF + kt * 32 + c4 * 4);
            f16x4 hv;
            hv.x = (_Float16)v.x; hv.y = (_Float16)v.y;
            hv.z = (_Float16)v.z; hv.w = (_Float16)v.w;
            *(f16x4*)(As + row * LDA + c4 * 4) = hv;
        }
        // --- stage B hi/lo: 128 n x 32 k fp16 (pre-transposed, contiguous k) ---
#pragma unroll
        for (int c = tid; c < 512; c += 256) {    // 16B fp16 granules
            int n = c >> 2, k8 = c & 3;
            f16x8 vh = *(const f16x8*)(Bhi + (size_t)(n0 + n) * FF + kt * 32 + k8 * 8);
            *(f16x8*)(Bh + n * LDA + k8 * 8) = vh;
            f16x8 vl = *(const f16x8*)(Blo + (size_t)(n0 + n) * FF + kt * 32 + k8 * 8);
            *(f16x8*)(Bl + n * LDA + k8 * 8) = vl;
        }
        __syncthreads();

        f16x8 af[4], bhf[4], blf[4];
#pragma unroll
        for (int mt = 0; mt < 4; ++mt)
            af[mt] = *(const f16x8*)(As + (wm * 64 + mt * 16 + l16) * LDA + q * 8);
#pragma unroll
        for (int nt = 0; nt < 4; ++nt) {
            bhf[nt] = *(const f16x8*)(Bh + (wn * 64 + nt * 16 + l16) * LDA + q * 8);
            blf[nt] = *(const f16x8*)(Bl + (wn * 64 + nt * 16 + l16) * LDA + q * 8);
        }
#pragma unroll
        for (int mt = 0; mt < 4; ++mt)
#pragma unroll
            for (int nt = 0; nt < 4; ++nt) {
                acc[mt][nt] = __builtin_amdgcn_mfma_f32_16x16x32_f16(af[mt], bhf[nt], acc[mt][nt], 0, 0, 0);
                acc[mt][nt] = __builtin_amdgcn_mfma_f32_16x16x32_f16(af[mt], blf[nt], acc[mt][nt], 0, 0, 0);
            }
        __syncthreads();
    }

    // epilogue: C/D layout col = lane&15, row = quad*4 + reg
#pragma unroll
    for (int mt = 0; mt < 4; ++mt)
#pragma unroll
        for (int r = 0; r < 4; ++r) {
            int m = m0 + wm * 64 + mt * 16 + q * 4 + r;
            if (m < NN) {
#pragma unroll
                for (int nt = 0; nt < 4; ++nt) {
                    int n = n0 + wn * 64 + nt * 16 + l16;
                    H[(size_t)m * FF + n] = (_Float16)acc[mt][nt][r];
                }
            }
        }
}

// ---------------------------------------------------------------------------
// Aggregation + bias + PReLU. One wave per row; lane owns 4 features.
// out[i] = prelu( dinv[i]*( sum_e w_e*h[src_e] + dinv[i]*h[i] ) + b, a )
// ---------------------------------------------------------------------------
__global__ __launch_bounds__(256) void agg_kernel(
    const _Float16* __restrict__ H, const int* __restrict__ rs,
    const int* __restrict__ csrc, const float* __restrict__ cw,
    const float* __restrict__ dinv, const float* __restrict__ bias,
    const float* __restrict__ a_ptr, float* __restrict__ out) {
    const int row  = blockIdx.x * 4 + (threadIdx.x >> 6);
    const int lane = threadIdx.x & 63;
    if (row >= NN) return;

    const float av = a_ptr[0];
    const float di = dinv[row];

    f16x4 hv = *(const f16x4*)(H + (size_t)row * FF + lane * 4);
    float ax = di * (float)hv.x;
    float ay = di * (float)hv.y;
    float az = di * (float)hv.z;
    float aw = di * (float)hv.w;

    int e   = rs[row];
    int end = rs[row + 1];
    for (; e + 1 < end; e += 2) {
        int   s0 = csrc[e],   s1 = csrc[e + 1];
        float w0 = cw[e],     w1 = cw[e + 1];
        f16x4 h0 = *(const f16x4*)(H + (size_t)s0 * FF + lane * 4);
        f16x4 h1 = *(const f16x4*)(H + (size_t)s1 * FF + lane * 4);
        ax += w0 * (float)h0.x + w1 * (float)h1.x;
        ay += w0 * (float)h0.y + w1 * (float)h1.y;
        az += w0 * (float)h0.z + w1 * (float)h1.z;
        aw += w0 * (float)h0.w + w1 * (float)h1.w;
    }
    if (e < end) {
        int   s0 = csrc[e];
        float w0 = cw[e];
        f16x4 h0 = *(const f16x4*)(H + (size_t)s0 * FF + lane * 4);
        ax += w0 * (float)h0.x;
        ay += w0 * (float)h0.y;
        az += w0 * (float)h0.z;
        aw += w0 * (float)h0.w;
    }

    f32x4 bv = *(const f32x4*)(bias + lane * 4);
    float r0 = di * ax + bv.x; r0 = (r0 >= 0.f) ? r0 : av * r0;
    float r1 = di * ay + bv.y; r1 = (r1 >= 0.f) ? r1 : av * r1;
    float r2 = di * az + bv.z; r2 = (r2 >= 0.f) ? r2 : av * r2;
    float r3 = di * aw + bv.w; r3 = (r3 >= 0.f) ? r3 : av * r3;
    f32x4 res = {r0, r1, r2, r3};
    *(f32x4*)(out + (size_t)row * FF + lane * 4) = res;
}

// ---------------------------------------------------------------------------
// Launch
// ---------------------------------------------------------------------------
extern "C" void kernel_launch(void* const* d_in, const int* in_sizes, int n_in,
                              void* d_out, int out_size, void* d_ws, size_t ws_size,
                              hipStream_t stream) {
    const float* x  = (const float*)d_in[0];
    const float* W1 = (const float*)d_in[1];
    const float* b1 = (const float*)d_in[2];
    const float* W2 = (const float*)d_in[3];
    const float* b2 = (const float*)d_in[4];
    const float* a  = (const float*)d_in[5];
    const int*   ei = (const int*)d_in[6];
    float* out = (float*)d_out;

    char* ws = (char*)d_ws;
    size_t off = 0;
    auto carve = [&](size_t bytes) -> char* {
        char* p = ws + off;
        off = (off + bytes + 255) & ~(size_t)255;
        return p;
    };
    int*      ec   = (int*)carve((size_t)NN * 4);
    int*      cnt  = (int*)carve((size_t)NN * 4);
    int*      rs   = (int*)carve((size_t)(NN + 1) * 4);
    float*    dinv = (float*)carve((size_t)NN * 4);
    int*      bsum = (int*)carve((size_t)NBLK * 4);
    int*      boff = (int*)carve((size_t)NBLK * 4);
    int*      csrc = (int*)carve((size_t)EE * 4);
    float*    cw   = (float*)carve((size_t)EE * 4);
    _Float16* wp   = (_Float16*)carve((size_t)4 * 65536 * 2);
    _Float16* h    = (_Float16*)carve((size_t)NN * FF * 2);

    hipMemsetAsync(ec, 0, (size_t)NN * 4, stream);
    hipMemsetAsync(cnt, 0, (size_t)NN * 4, stream);

    count_kernel<<<(EE + 255) / 256, 256, 0, stream>>>(ei, ec);
    scan_part <<<NBLK, 256, 0, stream>>>(ec, bsum);
    scan_mid  <<<1, 256, 0, stream>>>(bsum, boff, rs);
    scan_final<<<NBLK, 256, 0, stream>>>(ec, boff, rs, dinv);
    fill_kernel<<<(EE + 255) / 256, 256, 0, stream>>>(ei, rs, cnt, dinv, csrc, cw);
    packw_kernel<<<256, 256, 0, stream>>>(W1, W2, wp);

    // layer 1
    gemm_kernel<<<dim3(2, 391), 256, 0, stream>>>(x, wp + 0 * 65536, wp + 1 * 65536, h);
    agg_kernel<<<(NN + 3) / 4, 256, 0, stream>>>(h, rs, csrc, cw, dinv, b1, a, out);
    // layer 2
    gemm_kernel<<<dim3(2, 391), 256, 0, stream>>>(out, wp + 2 * 65536, wp + 3 * 65536, h);
    agg_kernel<<<(NN + 3) / 4, 256, 0, stream>>>(h, rs, csrc, cw, dinv, b2, a, out);
}

// Round 3
// 393.215 us; speedup vs baseline: 1.2530x; 1.0812x over previous
//
#include <hip/hip_runtime.h>

// Problem constants
#define NN 50000
#define EE 800000
#define FF 256   // IN = HID = PROJ = 256
#define NBLK 196 // ceil(NN/256)

typedef float    f32x4 __attribute__((ext_vector_type(4)));
typedef _Float16 f16x8 __attribute__((ext_vector_type(8)));
typedef _Float16 f16x4 __attribute__((ext_vector_type(4)));

// ---------------------------------------------------------------------------
// CSR build kernels
// ---------------------------------------------------------------------------

// ec[d] += 1 for every edge with dst d (self-loops handled analytically later)
__global__ void count_kernel(const int* __restrict__ ei, int* __restrict__ ec) {
    int e = blockIdx.x * 256 + threadIdx.x;
    if (e < EE) atomicAdd(&ec[ei[EE + e]], 1);
}

// ---- two-level scan: part-sums -> scan of 196 partials -> final scan ------

__global__ __launch_bounds__(256) void scan_part(const int* __restrict__ ec,
                                                 int* __restrict__ bsum) {
    int i = blockIdx.x * 256 + threadIdx.x;
    int v = (i < NN) ? ec[i] : 0;
#pragma unroll
    for (int d = 1; d < 64; d <<= 1) v += __shfl_xor(v, d);
    __shared__ int wt[4];
    int lane = threadIdx.x & 63, wid = threadIdx.x >> 6;
    if (lane == 0) wt[wid] = v;
    __syncthreads();
    if (threadIdx.x == 0)
        bsum[blockIdx.x] = wt[0] + wt[1] + wt[2] + wt[3];
}

__global__ __launch_bounds__(256) void scan_mid(const int* __restrict__ bsum,
                                                int* __restrict__ boff,
                                                int* __restrict__ rs) {
    const int t = threadIdx.x;
    int v = (t < NBLK) ? bsum[t] : 0;
    int lane = t & 63, wid = t >> 6;
    int x = v;
#pragma unroll
    for (int d = 1; d < 64; d <<= 1) {
        int u = __shfl_up(x, d);
        if (lane >= d) x += u;
    }
    __shared__ int wt[4];
    if (lane == 63) wt[wid] = x;
    __syncthreads();
    int add = 0;
    for (int wi = 0; wi < wid; ++wi) add += wt[wi];
    x += add;                                   // inclusive scan
    if (t < NBLK) boff[t] = x - v;              // exclusive
    if (t == NBLK - 1) rs[NN] = x;              // total == EE
}

__global__ __launch_bounds__(256) void scan_final(const int* __restrict__ ec,
                                                  const int* __restrict__ boff,
                                                  int* __restrict__ rs,
                                                  float* __restrict__ dinv) {
    int i = blockIdx.x * 256 + threadIdx.x;
    int v = (i < NN) ? ec[i] : 0;
    int lane = threadIdx.x & 63, wid = threadIdx.x >> 6;
    int x = v;
#pragma unroll
    for (int d = 1; d < 64; d <<= 1) {
        int u = __shfl_up(x, d);
        if (lane >= d) x += u;
    }
    __shared__ int wt[4];
    if (lane == 63) wt[wid] = x;
    __syncthreads();
    int add = 0;
    for (int wi = 0; wi < wid; ++wi) add += wt[wi];
    x += add;                                   // block-inclusive
    if (i < NN) {
        rs[i]   = x - v + boff[blockIdx.x];     // global exclusive
        dinv[i] = rsqrtf((float)(v + 1));       // deg = edges + self-loop
    }
}

// scatter edges into CSR slots; pack (src, dinv[src]) into one 8B record
__global__ void fill_kernel(const int* __restrict__ ei, const int* __restrict__ rs,
                            int* __restrict__ cnt, const float* __restrict__ dinv,
                            int2* __restrict__ ecw) {
    int e = blockIdx.x * 256 + threadIdx.x;
    if (e >= EE) return;
    int s = ei[e];
    int d = ei[EE + e];
    int p = rs[d] + atomicAdd(&cnt[d], 1);
    ecw[p] = make_int2(s, __float_as_int(dinv[s]));
}

// ---------------------------------------------------------------------------
// W pack: fp32 [K=256][N=256] row-major -> transposed fp16 hi/lo [n][k]
// ---------------------------------------------------------------------------
__global__ void packw_kernel(const float* __restrict__ W1, const float* __restrict__ W2,
                             _Float16* __restrict__ wp) {
    int idx = blockIdx.x * 256 + threadIdx.x;     // 65536 threads
    int k = idx >> 8, n = idx & 255;
    float w1 = W1[k * 256 + n];
    _Float16 h1 = (_Float16)w1;
    wp[0 * 65536 + n * 256 + k] = h1;
    wp[1 * 65536 + n * 256 + k] = (_Float16)(w1 - (float)h1);
    float w2 = W2[k * 256 + n];
    _Float16 h2 = (_Float16)w2;
    wp[2 * 65536 + n * 256 + k] = h2;
    wp[3 * 65536 + n * 256 + k] = (_Float16)(w2 - (float)h2);
}

// ---------------------------------------------------------------------------
// GEMM: H(fp16)[50000][256] = X @ W via fp16 MFMA, W = Whi + Wlo.
// A input is fp32 (layer 1) or fp16 (layer 2) -- templated stager.
// ---------------------------------------------------------------------------
#define LDA 40   // padded fp16 leading dim (32 + 8): 2-way LDS bank aliasing only

template<typename AT>
__global__ __launch_bounds__(256) void gemm_kernel(
    const AT* __restrict__ X, const _Float16* __restrict__ Bhi,
    const _Float16* __restrict__ Blo, _Float16* __restrict__ H) {
    __shared__ _Float16 As[128 * LDA];
    __shared__ _Float16 Bh[128 * LDA];
    __shared__ _Float16 Bl[128 * LDA];

    const int tid  = threadIdx.x;
    const int lane = tid & 63;
    const int w    = tid >> 6;
    const int wm   = w & 1, wn = w >> 1;
    const int q    = lane >> 4;       // quad -> k-group
    const int l16  = lane & 15;
    const int m0   = blockIdx.y * 128;
    const int n0   = blockIdx.x * 128;

    f32x4 acc[4][4] = {};             // [mt][nt], 16 tiles of 16x16

    for (int kt = 0; kt < 8; ++kt) {
        if constexpr (sizeof(AT) == 4) {
            // fp32 X: 128 rows x 32 k, convert to fp16
#pragma unroll
            for (int c = tid; c < 1024; c += 256) {   // 16B fp32 granules
                int row = c >> 3, c4 = c & 7;
                int gm = m0 + row; if (gm > NN - 1) gm = NN - 1;
                f32x4 v = *(const f32x4*)((const float*)X + (size_t)gm * FF + kt * 32 + c4 * 4);
                f16x4 hv;
                hv.x = (_Float16)v.x; hv.y = (_Float16)v.y;
                hv.z = (_Float16)v.z; hv.w = (_Float16)v.w;
                *(f16x4*)(As + row * LDA + c4 * 4) = hv;
            }
        } else {
            // fp16 X: straight 16B copies
#pragma unroll
            for (int c = tid; c < 512; c += 256) {
                int row = c >> 2, k8 = c & 3;
                int gm = m0 + row; if (gm > NN - 1) gm = NN - 1;
                f16x8 v = *(const f16x8*)((const _Float16*)X + (size_t)gm * FF + kt * 32 + k8 * 8);
                *(f16x8*)(As + row * LDA + k8 * 8) = v;
            }
        }
        // --- stage B hi/lo: 128 n x 32 k fp16 (pre-transposed, contiguous k) ---
#pragma unroll
        for (int c = tid; c < 512; c += 256) {    // 16B fp16 granules
            int n = c >> 2, k8 = c & 3;
            f16x8 vh = *(const f16x8*)(Bhi + (size_t)(n0 + n) * FF + kt * 32 + k8 * 8);
            *(f16x8*)(Bh + n * LDA + k8 * 8) = vh;
            f16x8 vl = *(const f16x8*)(Blo + (size_t)(n0 + n) * FF + kt * 32 + k8 * 8);
            *(f16x8*)(Bl + n * LDA + k8 * 8) = vl;
        }
        __syncthreads();

        f16x8 af[4], bhf[4], blf[4];
#pragma unroll
        for (int mt = 0; mt < 4; ++mt)
            af[mt] = *(const f16x8*)(As + (wm * 64 + mt * 16 + l16) * LDA + q * 8);
#pragma unroll
        for (int nt = 0; nt < 4; ++nt) {
            bhf[nt] = *(const f16x8*)(Bh + (wn * 64 + nt * 16 + l16) * LDA + q * 8);
            blf[nt] = *(const f16x8*)(Bl + (wn * 64 + nt * 16 + l16) * LDA + q * 8);
        }
#pragma unroll
        for (int mt = 0; mt < 4; ++mt)
#pragma unroll
            for (int nt = 0; nt < 4; ++nt) {
                acc[mt][nt] = __builtin_amdgcn_mfma_f32_16x16x32_f16(af[mt], bhf[nt], acc[mt][nt], 0, 0, 0);
                acc[mt][nt] = __builtin_amdgcn_mfma_f32_16x16x32_f16(af[mt], blf[nt], acc[mt][nt], 0, 0, 0);
            }
        __syncthreads();
    }

    // epilogue: C/D layout col = lane&15, row = quad*4 + reg
#pragma unroll
    for (int mt = 0; mt < 4; ++mt)
#pragma unroll
        for (int r = 0; r < 4; ++r) {
            int m = m0 + wm * 64 + mt * 16 + q * 4 + r;
            if (m < NN) {
#pragma unroll
                for (int nt = 0; nt < 4; ++nt) {
                    int n = n0 + wn * 64 + nt * 16 + l16;
                    H[(size_t)m * FF + n] = (_Float16)acc[mt][nt][r];
                }
            }
        }
}

// ---------------------------------------------------------------------------
// Aggregation + bias + PReLU. One wave per row; lane owns 4 features.
// out[i] = prelu( dinv[i]*( sum_e w_e*h[src_e] + dinv[i]*h[i] ) + b, a )
// 4x unrolled with independent packed index loads for memory-level parallelism.
// OT = _Float16 (layer 1, feeds GEMM2) or float (layer 2, final output).
// ---------------------------------------------------------------------------
template<typename OT>
__global__ __launch_bounds__(256) void agg_kernel(
    const _Float16* __restrict__ H, const int* __restrict__ rs,
    const int2* __restrict__ ecw, const float* __restrict__ dinv,
    const float* __restrict__ bias, const float* __restrict__ a_ptr,
    OT* __restrict__ out) {
    const int row  = blockIdx.x * 4 + (threadIdx.x >> 6);
    const int lane = threadIdx.x & 63;
    if (row >= NN) return;

    const float av = a_ptr[0];
    const float di = dinv[row];

    f16x4 hv = *(const f16x4*)(H + (size_t)row * FF + lane * 4);
    float ax = di * (float)hv.x;
    float ay = di * (float)hv.y;
    float az = di * (float)hv.z;
    float aw = di * (float)hv.w;

    int e   = rs[row];
    int end = rs[row + 1];
    for (; e + 3 < end; e += 4) {
        int2 p0 = ecw[e], p1 = ecw[e + 1], p2 = ecw[e + 2], p3 = ecw[e + 3];
        f16x4 h0 = *(const f16x4*)(H + (size_t)p0.x * FF + lane * 4);
        f16x4 h1 = *(const f16x4*)(H + (size_t)p1.x * FF + lane * 4);
        f16x4 h2 = *(const f16x4*)(H + (size_t)p2.x * FF + lane * 4);
        f16x4 h3 = *(const f16x4*)(H + (size_t)p3.x * FF + lane * 4);
        float w0 = __int_as_float(p0.y), w1 = __int_as_float(p1.y);
        float w2 = __int_as_float(p2.y), w3 = __int_as_float(p3.y);
        ax += w0 * (float)h0.x + w1 * (float)h1.x + w2 * (float)h2.x + w3 * (float)h3.x;
        ay += w0 * (float)h0.y + w1 * (float)h1.y + w2 * (float)h2.y + w3 * (float)h3.y;
        az += w0 * (float)h0.z + w1 * (float)h1.z + w2 * (float)h2.z + w3 * (float)h3.z;
        aw += w0 * (float)h0.w + w1 * (float)h1.w + w2 * (float)h2.w + w3 * (float)h3.w;
    }
    for (; e < end; ++e) {
        int2 p = ecw[e];
        float w0 = __int_as_float(p.y);
        f16x4 h0 = *(const f16x4*)(H + (size_t)p.x * FF + lane * 4);
        ax += w0 * (float)h0.x;
        ay += w0 * (float)h0.y;
        az += w0 * (float)h0.z;
        aw += w0 * (float)h0.w;
    }

    f32x4 bv = *(const f32x4*)(bias + lane * 4);
    float r0 = di * ax + bv.x; r0 = (r0 >= 0.f) ? r0 : av * r0;
    float r1 = di * ay + bv.y; r1 = (r1 >= 0.f) ? r1 : av * r1;
    float r2 = di * az + bv.z; r2 = (r2 >= 0.f) ? r2 : av * r2;
    float r3 = di * aw + bv.w; r3 = (r3 >= 0.f) ? r3 : av * r3;
    if constexpr (sizeof(OT) == 4) {
        f32x4 res = {r0, r1, r2, r3};
        *(f32x4*)((float*)out + (size_t)row * FF + lane * 4) = res;
    } else {
        f16x4 res;
        res.x = (_Float16)r0; res.y = (_Float16)r1;
        res.z = (_Float16)r2; res.w = (_Float16)r3;
        *(f16x4*)((_Float16*)out + (size_t)row * FF + lane * 4) = res;
    }
}

// ---------------------------------------------------------------------------
// Launch
// ---------------------------------------------------------------------------
extern "C" void kernel_launch(void* const* d_in, const int* in_sizes, int n_in,
                              void* d_out, int out_size, void* d_ws, size_t ws_size,
                              hipStream_t stream) {
    const float* x  = (const float*)d_in[0];
    const float* W1 = (const float*)d_in[1];
    const float* b1 = (const float*)d_in[2];
    const float* W2 = (const float*)d_in[3];
    const float* b2 = (const float*)d_in[4];
    const float* a  = (const float*)d_in[5];
    const int*   ei = (const int*)d_in[6];
    float* out = (float*)d_out;

    char* ws = (char*)d_ws;
    size_t off = 0;
    auto carve = [&](size_t bytes) -> char* {
        char* p = ws + off;
        off = (off + bytes + 255) & ~(size_t)255;
        return p;
    };
    int*      ec   = (int*)carve((size_t)NN * 4);
    int*      cnt  = (int*)carve((size_t)NN * 4);
    int*      rs   = (int*)carve((size_t)(NN + 1) * 4);
    float*    dinv = (float*)carve((size_t)NN * 4);
    int*      bsum = (int*)carve((size_t)NBLK * 4);
    int*      boff = (int*)carve((size_t)NBLK * 4);
    int2*     ecw  = (int2*)carve((size_t)EE * 8);
    _Float16* wp   = (_Float16*)carve((size_t)4 * 65536 * 2);
    _Float16* h    = (_Float16*)carve((size_t)NN * FF * 2);
    _Float16* h1   = (_Float16*)carve((size_t)NN * FF * 2);

    hipMemsetAsync(ec, 0, (size_t)NN * 4, stream);
    hipMemsetAsync(cnt, 0, (size_t)NN * 4, stream);

    count_kernel<<<(EE + 255) / 256, 256, 0, stream>>>(ei, ec);
    scan_part <<<NBLK, 256, 0, stream>>>(ec, bsum);
    scan_mid  <<<1, 256, 0, stream>>>(bsum, boff, rs);
    scan_final<<<NBLK, 256, 0, stream>>>(ec, boff, rs, dinv);
    fill_kernel<<<(EE + 255) / 256, 256, 0, stream>>>(ei, rs, cnt, dinv, ecw);
    packw_kernel<<<256, 256, 0, stream>>>(W1, W2, wp);

    // layer 1: GEMM (fp32 A) -> agg (fp16 out, feeds GEMM2)
    gemm_kernel<float><<<dim3(2, 391), 256, 0, stream>>>(x, wp + 0 * 65536, wp + 1 * 65536, h);
    agg_kernel<_Float16><<<(NN + 3) / 4, 256, 0, stream>>>(h, rs, ecw, dinv, b1, a, h1);
    // layer 2: GEMM (fp16 A) -> agg (fp32 out, final)
    gemm_kernel<_Float16><<<dim3(2, 391), 256, 0, stream>>>(h1, wp + 2 * 65536, wp + 3 * 65536, h);
    agg_kernel<float><<<(NN + 3) / 4, 256, 0, stream>>>(h, rs, ecw, dinv, b2, a, out);
}